// Round 8
// baseline (295.204 us; speedup 1.0000x reference)
//
#include <hip/hip_runtime.h>
#include <hip/hip_bf16.h>

// GATNet 2-layer GAT, N=50000, E=800000 (+N self loops). f32 in/out, bf16 MFMA
// internally. Round-8: gemm0/gemm1 ct-loop split across blockIdx.y (4x / 2x
// more blocks) to fix latency-bound starvation (occ 22%, VALU 7% in r7).
// agg kernels unchanged from r7 (uint4 16-lane-group gathers).

typedef __attribute__((ext_vector_type(8))) short bf8_t;   // 8 x bf16 (4 VGPRs)
typedef __attribute__((ext_vector_type(4))) float f4_t;

__device__ inline short f2bf(float f) {
    return (short)__builtin_bit_cast(unsigned short, __float2bfloat16(f));
}
__device__ inline float blo(unsigned int p) { return __uint_as_float(p << 16); }
__device__ inline float bhi(unsigned int p) { return __uint_as_float(p & 0xffff0000u); }
__device__ inline float lrexp(float e) {
    e = (e > 0.f) ? e : 0.2f * e;          // leaky_relu(0.2); |e|<~12 -> exp safe
    return __expf(e);
}

// ---- init: zero counters + f32->bf16 weight prep + combined biases ----
__global__ void k_init(const float* __restrict__ W0, const float* __restrict__ lW0,
                       const float* __restrict__ W1, const float* __restrict__ lW1,
                       const float* __restrict__ b0, const float* __restrict__ lb0,
                       const float* __restrict__ b1, const float* __restrict__ lb1,
                       short* __restrict__ Wc0, short* __restrict__ lWc0,
                       short* __restrict__ Wc1, short* __restrict__ lWc1,
                       float* __restrict__ bc0, float* __restrict__ bc1,
                       int* __restrict__ cnt, int N) {
    int i = blockIdx.x * blockDim.x + threadIdx.x;
    if (i < N) cnt[i] = 0;
    if (i < 16384)       Wc0[i]          = f2bf(W0[i]);
    else if (i < 32768)  lWc0[i - 16384] = f2bf(lW0[i - 16384]);
    else if (i < 36864)  Wc1[i - 32768]  = f2bf(W1[i - 32768]);
    else if (i < 40960)  lWc1[i - 36864] = f2bf(lW1[i - 36864]);
    if (i < 128) bc0[i] = b0[i] + lb0[i];
    else if (i < 160) bc1[i - 128] = b1[i - 128] + lb1[i - 128];
}

// ---------------- CSR build ----------------

__global__ void k_count(const int* __restrict__ ei, int* __restrict__ deg, int E, int N) {
    int e = blockIdx.x * blockDim.x + threadIdx.x;
    if (e >= E + N) return;
    int dst = (e < E) ? ei[E + e] : (e - E);   // self-loops appended
    atomicAdd(&deg[dst], 1);
}

__global__ __launch_bounds__(1024) void k_scan1(const int* __restrict__ deg,
                                                int* __restrict__ rowstart,
                                                int* __restrict__ bsum, int n) {
    __shared__ int buf[1024];
    int tid = threadIdx.x, i = blockIdx.x * 1024 + tid;
    int v = (i < n) ? deg[i] : 0;
    buf[tid] = v;
    __syncthreads();
    for (int off = 1; off < 1024; off <<= 1) {
        int t = (tid >= off) ? buf[tid - off] : 0;
        __syncthreads();
        buf[tid] += t;
        __syncthreads();
    }
    if (i < n) rowstart[i] = buf[tid] - v;     // local exclusive
    if (tid == 1023) bsum[blockIdx.x] = buf[1023];
}

__global__ void k_scan2(const int* __restrict__ bsum, int* __restrict__ bcar,
                        int* __restrict__ rowstart, int nb, int n) {
    int lane = threadIdx.x;
    int v = (lane < nb) ? bsum[lane] : 0;
    int s = v;
    #pragma unroll
    for (int off = 1; off < 64; off <<= 1) {
        int t = __shfl_up(s, off);
        if (lane >= off) s += t;
    }
    if (lane < nb) bcar[lane] = s - v;
    if (lane == 63) rowstart[n] = s;
}

__global__ __launch_bounds__(1024) void k_scan3(int* __restrict__ rowstart,
                                                const int* __restrict__ bcar,
                                                int* __restrict__ cur, int n) {
    int i = blockIdx.x * 1024 + threadIdx.x;
    if (i < n) {
        int r = rowstart[i] + bcar[blockIdx.x];
        rowstart[i] = r;
        cur[i] = r;
    }
}

__global__ void k_fill(const int* __restrict__ ei, int* __restrict__ cur,
                       unsigned short* __restrict__ esrc, int E, int N) {
    int e = blockIdx.x * blockDim.x + threadIdx.x;
    if (e >= E + N) return;
    int src, dst;
    if (e < E) { src = ei[e]; dst = ei[E + e]; }
    else       { src = e - E; dst = e - E; }
    int pos = atomicAdd(&cur[dst], 1);
    esrc[pos] = (unsigned short)src;           // N < 65536
}

// ---------------- GEMM0 + fused att0 (ct-split: blockIdx.y = 0..3) ----------
// y=0: cts 0-3 (h0, heads 0-1)  y=1: cts 4-7 (h0, heads 2-3)
// y=2: cts 8-11 (skip)          y=3: cts 12-15 (skip)
// A-frag: lane holds A[m=lane&15][k=(lane>>4)*8+j]; B-frag: B[k][n=lane&15]
// C/D  : col=lane&15, row=(lane>>4)*4+reg  (m89-verified)

__global__ __launch_bounds__(256) void k_gemm0(
    const float* __restrict__ x,
    const short* __restrict__ Wc0, const short* __restrict__ lWc0,
    const float* __restrict__ as0, const float* __restrict__ ad0,
    __hip_bfloat16* __restrict__ h0, __hip_bfloat16* __restrict__ skipb,
    float* __restrict__ a0s, float* __restrict__ a0d, int N) {
    int wv = threadIdx.x >> 6, lane = threadIdx.x & 63;
    int rowbase = blockIdx.x * 64 + wv * 16;
    int y = blockIdx.y;                        // ct-group
    int m = lane & 15, q = lane >> 4;
    int arow = rowbase + m; if (arow >= N) arow = N - 1;
    bf8_t a[4];
    #pragma unroll
    for (int kb = 0; kb < 4; kb++) {
        const float4* px = (const float4*)(x + (size_t)arow * 128 + kb * 32 + q * 8);
        float4 lo = px[0], hi = px[1];
        bf8_t f;
        f[0] = f2bf(lo.x); f[1] = f2bf(lo.y); f[2] = f2bf(lo.z); f[3] = f2bf(lo.w);
        f[4] = f2bf(hi.x); f[5] = f2bf(hi.y); f[6] = f2bf(hi.z); f[7] = f2bf(hi.w);
        a[kb] = f;
    }
    bool is_h0 = (y < 2);
    float sacc[2][4], dacc[2][4];
    #pragma unroll
    for (int h = 0; h < 2; h++)
        #pragma unroll
        for (int r = 0; r < 4; r++) { sacc[h][r] = 0.f; dacc[h][r] = 0.f; }

    #pragma unroll
    for (int lc = 0; lc < 4; lc++) {
        int ct = y * 4 + lc;                   // global ct 0..15
        const short* Wp = is_h0 ? Wc0 : lWc0;
        int cb = (ct & 7) * 16;
        f4_t acc = {0.f, 0.f, 0.f, 0.f};
        #pragma unroll
        for (int kb = 0; kb < 4; kb++) {
            bf8_t b = *(const bf8_t*)(Wp + (size_t)(cb + m) * 128 + kb * 32 + q * 8);
            acc = __builtin_amdgcn_mfma_f32_16x16x32_bf16(a[kb], b, acc, 0, 0, 0);
        }
        if (is_h0) {
            int lh = lc >> 1;                  // local head 0,1
            float ws = as0[cb + m], wd = ad0[cb + m];
            #pragma unroll
            for (int r = 0; r < 4; r++) {
                sacc[lh][r] += acc[r] * ws;
                dacc[lh][r] += acc[r] * wd;
            }
        }
        #pragma unroll
        for (int r = 0; r < 4; r++) {
            int row = rowbase + q * 4 + r;
            if (row < N) {
                int col = cb + m;
                if (is_h0) h0[(size_t)row * 128 + col]    = __float2bfloat16(acc[r]);
                else       skipb[(size_t)row * 128 + col] = __float2bfloat16(acc[r]);
            }
        }
    }
    if (is_h0) {
        #pragma unroll
        for (int h = 0; h < 2; h++)
            #pragma unroll
            for (int r = 0; r < 4; r++) {
                float s = sacc[h][r], d = dacc[h][r];
                #pragma unroll
                for (int off = 1; off < 16; off <<= 1) {
                    s += __shfl_xor(s, off);
                    d += __shfl_xor(d, off);
                }
                sacc[h][r] = s; dacc[h][r] = d;
            }
        if (m < 2) {
            #pragma unroll
            for (int r = 0; r < 4; r++) {
                int row = rowbase + q * 4 + r;
                if (row < N) {
                    float sv = (m == 0) ? sacc[0][r] : sacc[1][r];
                    float dv = (m == 0) ? dacc[0][r] : dacc[1][r];
                    a0s[row * 4 + y * 2 + m] = sv;
                    a0d[row * 4 + y * 2 + m] = dv;
                }
            }
        }
    }
}

// ---------------- GEMM1 + fused att1 (ct-split: blockIdx.y = 0..1) ----------
// y=0: cts 0-1 (h1 + att)   y=1: cts 2-3 (skip -> d_out)

__global__ __launch_bounds__(256) void k_gemm1(
    const __hip_bfloat16* __restrict__ hin,
    const short* __restrict__ Wc1, const short* __restrict__ lWc1,
    const float* __restrict__ as1, const float* __restrict__ ad1,
    __hip_bfloat16* __restrict__ h1, float* __restrict__ skipb /* = d_out */,
    float* __restrict__ a1s, float* __restrict__ a1d, int N) {
    int wv = threadIdx.x >> 6, lane = threadIdx.x & 63;
    int rowbase = blockIdx.x * 64 + wv * 16;
    int y = blockIdx.y;
    int m = lane & 15, q = lane >> 4;
    int arow = rowbase + m; if (arow >= N) arow = N - 1;
    const short* xs = (const short*)hin;
    bf8_t a[4];
    #pragma unroll
    for (int kb = 0; kb < 4; kb++)
        a[kb] = *(const bf8_t*)(xs + (size_t)arow * 128 + kb * 32 + q * 8);
    bool is_h1 = (y == 0);
    float sacc[4], dacc[4];
    #pragma unroll
    for (int r = 0; r < 4; r++) { sacc[r] = 0.f; dacc[r] = 0.f; }
    #pragma unroll
    for (int lc = 0; lc < 2; lc++) {
        const short* Wp = is_h1 ? Wc1 : lWc1;
        int cb = lc * 16;
        f4_t acc = {0.f, 0.f, 0.f, 0.f};
        #pragma unroll
        for (int kb = 0; kb < 4; kb++) {
            bf8_t b = *(const bf8_t*)(Wp + (size_t)(cb + m) * 128 + kb * 32 + q * 8);
            acc = __builtin_amdgcn_mfma_f32_16x16x32_bf16(a[kb], b, acc, 0, 0, 0);
        }
        if (is_h1) {
            float ws = as1[cb + m], wd = ad1[cb + m];
            #pragma unroll
            for (int r = 0; r < 4; r++) {
                sacc[r] += acc[r] * ws;
                dacc[r] += acc[r] * wd;
            }
        }
        #pragma unroll
        for (int r = 0; r < 4; r++) {
            int row = rowbase + q * 4 + r;
            if (row < N) {
                size_t idx = (size_t)row * 32 + cb + m;
                if (is_h1) h1[idx] = __float2bfloat16(acc[r]);
                else       skipb[idx] = acc[r];
            }
        }
    }
    if (is_h1) {
        #pragma unroll
        for (int r = 0; r < 4; r++) {
            float s = sacc[r], d = dacc[r];
            #pragma unroll
            for (int off = 1; off < 16; off <<= 1) {
                s += __shfl_xor(s, off);
                d += __shfl_xor(d, off);
            }
            if (m == 0) {
                int row = rowbase + q * 4 + r;
                if (row < N) { a1s[row] = s; a1d[row] = d; }
            }
        }
    }
}

// ---------------- aggregation: 16-lane edge groups, 1 wave/node ----------------

__global__ __launch_bounds__(256) void k_agg0(
    const int* __restrict__ rowstart, const unsigned short* __restrict__ esrc,
    const unsigned int* __restrict__ h0u,              // row = 64 uints (bf16x2)
    const float* __restrict__ a0s, const float* __restrict__ a0d,
    const float* __restrict__ bc0,                     // bias0+linb0 [128]
    unsigned int* __restrict__ h1in_u,                 // in: skip0 bf16, out: ELU
    int n) {
    int node = (blockIdx.x * 256 + threadIdx.x) >> 6;
    int lane = threadIdx.x & 63;
    if (node >= n) return;
    int g = lane >> 4, t = lane & 15, hd = t >> 2;
    float ad = a0d[node * 4 + hd];
    int s0 = rowstart[node], s1 = rowstart[node + 1];
    float den = 0.f;
    float acc[8];
    #pragma unroll
    for (int k = 0; k < 8; k++) acc[k] = 0.f;
    int i = s0 + g;
    for (; i + 4 < s1; i += 8) {               // 2 edges/group/iter = 8/wave
        int sA = esrc[i], sB = esrc[i + 4];
        float eA = a0s[sA * 4 + hd] + ad;
        float eB = a0s[sB * 4 + hd] + ad;
        uint4 pA = *(const uint4*)(h0u + (size_t)sA * 64 + t * 4);
        uint4 pB = *(const uint4*)(h0u + (size_t)sB * 64 + t * 4);
        float wA = lrexp(eA), wB = lrexp(eB);
        den += wA + wB;
        acc[0] += wA * blo(pA.x) + wB * blo(pB.x);
        acc[1] += wA * bhi(pA.x) + wB * bhi(pB.x);
        acc[2] += wA * blo(pA.y) + wB * blo(pB.y);
        acc[3] += wA * bhi(pA.y) + wB * bhi(pB.y);
        acc[4] += wA * blo(pA.z) + wB * blo(pB.z);
        acc[5] += wA * bhi(pA.z) + wB * bhi(pB.z);
        acc[6] += wA * blo(pA.w) + wB * blo(pB.w);
        acc[7] += wA * bhi(pA.w) + wB * bhi(pB.w);
    }
    for (; i < s1; i += 4) {
        int s = esrc[i];
        float wv = lrexp(a0s[s * 4 + hd] + ad);
        uint4 p = *(const uint4*)(h0u + (size_t)s * 64 + t * 4);
        den += wv;
        acc[0] += wv * blo(p.x); acc[1] += wv * bhi(p.x);
        acc[2] += wv * blo(p.y); acc[3] += wv * bhi(p.y);
        acc[4] += wv * blo(p.z); acc[5] += wv * bhi(p.z);
        acc[6] += wv * blo(p.w); acc[7] += wv * bhi(p.w);
    }
    #pragma unroll
    for (int k = 0; k < 8; k++) {
        acc[k] += __shfl_xor(acc[k], 16);
        acc[k] += __shfl_xor(acc[k], 32);
    }
    den += __shfl_xor(den, 16);
    den += __shfl_xor(den, 32);
    if (g == 0) {
        float inv = 1.0f / (den + 1e-16f);
        uint4 sp = *(const uint4*)(h1in_u + (size_t)node * 64 + t * 4); // skip0
        int c0 = t * 8;
        float o[8];
        o[0] = acc[0] * inv + blo(sp.x) + bc0[c0 + 0];
        o[1] = acc[1] * inv + bhi(sp.x) + bc0[c0 + 1];
        o[2] = acc[2] * inv + blo(sp.y) + bc0[c0 + 2];
        o[3] = acc[3] * inv + bhi(sp.y) + bc0[c0 + 3];
        o[4] = acc[4] * inv + blo(sp.z) + bc0[c0 + 4];
        o[5] = acc[5] * inv + bhi(sp.z) + bc0[c0 + 5];
        o[6] = acc[6] * inv + blo(sp.w) + bc0[c0 + 6];
        o[7] = acc[7] * inv + bhi(sp.w) + bc0[c0 + 7];
        #pragma unroll
        for (int k = 0; k < 8; k++)
            o[k] = (o[k] > 0.f) ? o[k] : (__expf(o[k]) - 1.f);  // ELU
        uint4 res;
        res.x = (unsigned int)(unsigned short)f2bf(o[0]) | ((unsigned int)(unsigned short)f2bf(o[1]) << 16);
        res.y = (unsigned int)(unsigned short)f2bf(o[2]) | ((unsigned int)(unsigned short)f2bf(o[3]) << 16);
        res.z = (unsigned int)(unsigned short)f2bf(o[4]) | ((unsigned int)(unsigned short)f2bf(o[5]) << 16);
        res.w = (unsigned int)(unsigned short)f2bf(o[6]) | ((unsigned int)(unsigned short)f2bf(o[7]) << 16);
        *(uint4*)(h1in_u + (size_t)node * 64 + t * 4) = res;
    }
}

__global__ __launch_bounds__(256) void k_agg1(
    const int* __restrict__ rowstart, const unsigned short* __restrict__ esrc,
    const __hip_bfloat16* __restrict__ h1,
    const float* __restrict__ a1s, const float* __restrict__ a1d,
    const float* __restrict__ bc1,                     // bias1+linb1 [32]
    float* __restrict__ out, int n) {
    int node = (blockIdx.x * 256 + threadIdx.x) >> 6;
    int lane = threadIdx.x & 63;
    if (node >= n) return;
    int g = lane >> 4, t = lane & 15;
    float ad = a1d[node];
    int s0 = rowstart[node], s1 = rowstart[node + 1];
    const unsigned int* h1w = (const unsigned int*)h1;  // row = 16 uints
    float den = 0.f, acc0 = 0.f, acc1 = 0.f;
    int i = s0 + g;
    for (; i + 4 < s1; i += 8) {
        int sA = esrc[i], sB = esrc[i + 4];
        float eA = a1s[sA] + ad, eB = a1s[sB] + ad;
        unsigned int pA = h1w[(size_t)sA * 16 + t];
        unsigned int pB = h1w[(size_t)sB * 16 + t];
        float wA = lrexp(eA), wB = lrexp(eB);
        den += wA + wB;
        acc0 += wA * blo(pA) + wB * blo(pB);
        acc1 += wA * bhi(pA) + wB * bhi(pB);
    }
    for (; i < s1; i += 4) {
        int s = esrc[i];
        float wv = lrexp(a1s[s] + ad);
        unsigned int p = h1w[(size_t)s * 16 + t];
        den += wv; acc0 += wv * blo(p); acc1 += wv * bhi(p);
    }
    acc0 += __shfl_xor(acc0, 16); acc0 += __shfl_xor(acc0, 32);
    acc1 += __shfl_xor(acc1, 16); acc1 += __shfl_xor(acc1, 32);
    den  += __shfl_xor(den, 16);  den  += __shfl_xor(den, 32);
    if (g == 0) {
        float inv = 1.0f / (den + 1e-16f);
        int c0 = t * 2;
        size_t idx = (size_t)node * 32 + c0;
        float2 sk = *(const float2*)(out + idx);     // skip1
        float2 r;
        r.x = acc0 * inv + sk.x + bc1[c0];
        r.y = acc1 * inv + sk.y + bc1[c0 + 1];
        *(float2*)(out + idx) = r;
    }
}

// ---------------- launch ----------------

extern "C" void kernel_launch(void* const* d_in, const int* in_sizes, int n_in,
                              void* d_out, int out_size, void* d_ws, size_t ws_size,
                              hipStream_t stream) {
    const float* x   = (const float*)d_in[0];
    const int*   ei  = (const int*)d_in[1];
    const float* W0  = (const float*)d_in[2];
    const float* as0 = (const float*)d_in[3];
    const float* ad0 = (const float*)d_in[4];
    const float* b0  = (const float*)d_in[5];
    const float* lW0 = (const float*)d_in[6];
    const float* lb0 = (const float*)d_in[7];
    const float* W1  = (const float*)d_in[8];
    const float* as1 = (const float*)d_in[9];
    const float* ad1 = (const float*)d_in[10];
    const float* b1  = (const float*)d_in[11];
    const float* lW1 = (const float*)d_in[12];
    const float* lb1 = (const float*)d_in[13];
    float* out = (float*)d_out;

    const int N = in_sizes[0] / 128;
    const int E = in_sizes[1] / 2;
    const int T = E + N;
    const int NB = (N + 1023) / 1024;

    // workspace carve-up (256B aligned), ~29.5 MB
    char* w = (char*)d_ws;
    auto alloc = [&](size_t bytes) -> char* {
        char* p = w; w += (bytes + 255) / 256 * 256; return p;
    };
    int* rowstart  = (int*)alloc((size_t)(N + 1) * 4);
    int* cnt       = (int*)alloc((size_t)N * 4);          // deg, then fill-cursor
    int* bsum      = (int*)alloc(64 * 4);
    int* bcar      = (int*)alloc(64 * 4);
    unsigned short* esrc = (unsigned short*)alloc((size_t)T * 2);
    float* aS      = (float*)alloc((size_t)N * 4 * 4);    // layer0 [N,4]; layer1 [N]
    float* aD      = (float*)alloc((size_t)N * 4 * 4);
    __hip_bfloat16* hbuf = (__hip_bfloat16*)alloc((size_t)N * 128 * 2); // h0 / h1
    __hip_bfloat16* h1in = (__hip_bfloat16*)alloc((size_t)N * 128 * 2); // skip0 -> ELU
    short* Wc0  = (short*)alloc(16384 * 2);
    short* lWc0 = (short*)alloc(16384 * 2);
    short* Wc1  = (short*)alloc(4096 * 2);
    short* lWc1 = (short*)alloc(4096 * 2);
    float* bc0  = (float*)alloc(128 * 4);
    float* bc1  = (float*)alloc(32 * 4);

    // init (zero counters + weight prep + combined biases), then CSR build
    k_init<<<(N + 255) / 256, 256, 0, stream>>>(W0, lW0, W1, lW1, b0, lb0, b1, lb1,
                                                Wc0, lWc0, Wc1, lWc1, bc0, bc1, cnt, N);
    k_count<<<(T + 255) / 256, 256, 0, stream>>>(ei, cnt, E, N);
    k_scan1<<<NB, 1024, 0, stream>>>(cnt, rowstart, bsum, N);
    k_scan2<<<1, 64, 0, stream>>>(bsum, bcar, rowstart, NB, N);
    k_scan3<<<NB, 1024, 0, stream>>>(rowstart, bcar, cnt, N);
    k_fill<<<(T + 255) / 256, 256, 0, stream>>>(ei, cnt, esrc, E, N);

    // layer 0 (att fused into gemm; ct-split over blockIdx.y)
    k_gemm0<<<dim3((N + 63) / 64, 4), 256, 0, stream>>>(x, Wc0, lWc0, as0, ad0,
                                                        hbuf, h1in, aS, aD, N);
    k_agg0<<<(N + 3) / 4, 256, 0, stream>>>(rowstart, esrc, (const unsigned int*)hbuf,
                                            aS, aD, bc0, (unsigned int*)h1in, N);
    // layer 1 (h1 reuses hbuf; skip1 lives in d_out f32; att fused; ct-split)
    k_gemm1<<<dim3((N + 63) / 64, 2), 256, 0, stream>>>(h1in, Wc1, lWc1, as1, ad1,
                                                        hbuf, out, aS, aD, N);
    k_agg1<<<(N + 3) / 4, 256, 0, stream>>>(rowstart, esrc, hbuf, aS, aD,
                                            bc1, out, N);
}

// Round 10
// 281.894 us; speedup vs baseline: 1.0472x; 1.0472x over previous
//
#include <hip/hip_runtime.h>
#include <hip/hip_bf16.h>

// GATNet 2-layer GAT, N=50000, E=800000 (+N self loops). f32 in/out, bf16 MFMA.
// Round-9 (resubmit after GPU timeout): gemm kernels rebuilt around the
// transaction model (r7/r8 invariance => TA-throughput bound): weights
// pre-packed in MFMA fragment order (dense 1KB wave loads), outputs staged in
// wave-private LDS then drained with coalesced dwordx4 stores. Grids single-y.
// agg/CSR unchanged from r8.

typedef __attribute__((ext_vector_type(8))) short bf8_t;   // 8 x bf16 (4 VGPRs)
typedef __attribute__((ext_vector_type(4))) float f4_t;

__device__ inline short f2bf(float f) {
    return (short)__builtin_bit_cast(unsigned short, __float2bfloat16(f));
}
__device__ inline float blo(unsigned int p) { return __uint_as_float(p << 16); }
__device__ inline float bhi(unsigned int p) { return __uint_as_float(p & 0xffff0000u); }
__device__ inline float lrexp(float e) {
    e = (e > 0.f) ? e : 0.2f * e;          // leaky_relu(0.2); |e|<~12 -> exp safe
    return __expf(e);
}

// ---- init: zero counters + weights -> bf16 packed in MFMA-fragment order ----
// Wp[((ct*4+kb)*64 + lane)*8 + j] = W[ct*16 + (lane&15)][kb*32 + (lane>>4)*8 + j]
__global__ void k_init(const float* __restrict__ W0, const float* __restrict__ lW0,
                       const float* __restrict__ W1, const float* __restrict__ lW1,
                       const float* __restrict__ b0, const float* __restrict__ lb0,
                       const float* __restrict__ b1, const float* __restrict__ lb1,
                       short* __restrict__ Wp0, short* __restrict__ lWp0,
                       short* __restrict__ Wp1, short* __restrict__ lWp1,
                       float* __restrict__ bc0, float* __restrict__ bc1,
                       int* __restrict__ cnt, int N) {
    int i = blockIdx.x * blockDim.x + threadIdx.x;
    if (i < N) cnt[i] = 0;
    if (i < 16384) {
        int j = i & 7, lane = (i >> 3) & 63, kc = i >> 9;
        int kb = kc & 3, ct = kc >> 2;                  // ct 0..7
        int src = (ct * 16 + (lane & 15)) * 128 + kb * 32 + (lane >> 4) * 8 + j;
        Wp0[i]  = f2bf(W0[src]);
        lWp0[i] = f2bf(lW0[src]);
    }
    if (i < 4096) {
        int j = i & 7, lane = (i >> 3) & 63, kc = i >> 9;
        int kb = kc & 3, ct = kc >> 2;                  // ct 0..1
        int src = (ct * 16 + (lane & 15)) * 128 + kb * 32 + (lane >> 4) * 8 + j;
        Wp1[i]  = f2bf(W1[src]);
        lWp1[i] = f2bf(lW1[src]);
    }
    if (i < 128) bc0[i] = b0[i] + lb0[i];
    else if (i < 160) bc1[i - 128] = b1[i - 128] + lb1[i - 128];
}

// ---------------- CSR build ----------------

__global__ void k_count(const int* __restrict__ ei, int* __restrict__ deg, int E, int N) {
    int e = blockIdx.x * blockDim.x + threadIdx.x;
    if (e >= E + N) return;
    int dst = (e < E) ? ei[E + e] : (e - E);   // self-loops appended
    atomicAdd(&deg[dst], 1);
}

__global__ __launch_bounds__(1024) void k_scan1(const int* __restrict__ deg,
                                                int* __restrict__ rowstart,
                                                int* __restrict__ bsum, int n) {
    __shared__ int buf[1024];
    int tid = threadIdx.x, i = blockIdx.x * 1024 + tid;
    int v = (i < n) ? deg[i] : 0;
    buf[tid] = v;
    __syncthreads();
    for (int off = 1; off < 1024; off <<= 1) {
        int t = (tid >= off) ? buf[tid - off] : 0;
        __syncthreads();
        buf[tid] += t;
        __syncthreads();
    }
    if (i < n) rowstart[i] = buf[tid] - v;     // local exclusive
    if (tid == 1023) bsum[blockIdx.x] = buf[1023];
}

__global__ void k_scan2(const int* __restrict__ bsum, int* __restrict__ bcar,
                        int* __restrict__ rowstart, int nb, int n) {
    int lane = threadIdx.x;
    int v = (lane < nb) ? bsum[lane] : 0;
    int s = v;
    #pragma unroll
    for (int off = 1; off < 64; off <<= 1) {
        int t = __shfl_up(s, off);
        if (lane >= off) s += t;
    }
    if (lane < nb) bcar[lane] = s - v;
    if (lane == 63) rowstart[n] = s;
}

__global__ __launch_bounds__(1024) void k_scan3(int* __restrict__ rowstart,
                                                const int* __restrict__ bcar,
                                                int* __restrict__ cur, int n) {
    int i = blockIdx.x * 1024 + threadIdx.x;
    if (i < n) {
        int r = rowstart[i] + bcar[blockIdx.x];
        rowstart[i] = r;
        cur[i] = r;
    }
}

__global__ void k_fill(const int* __restrict__ ei, int* __restrict__ cur,
                       unsigned short* __restrict__ esrc, int E, int N) {
    int e = blockIdx.x * blockDim.x + threadIdx.x;
    if (e >= E + N) return;
    int src, dst;
    if (e < E) { src = ei[e]; dst = ei[E + e]; }
    else       { src = e - E; dst = e - E; }
    int pos = atomicAdd(&cur[dst], 1);
    esrc[pos] = (unsigned short)src;           // N < 65536
}

// ---------------- GEMM0 + fused att0 ----------------
// A-frag: lane holds A[m=lane&15][k=(lane>>4)*8+j]; B from packed tables.
// C/D  : col=lane&15, row=(lane>>4)*4+reg  (m89-verified)
// Output staged per-wave in LDS (stride 136 shorts, 16B-aligned rows), drained
// with coalesced dwordx4 stores. No cross-wave sharing -> no barriers.

#define TSTR 136   // LDS tile row stride in shorts (272B, 16B-aligned)

__global__ __launch_bounds__(256) void k_gemm0(
    const float* __restrict__ x,
    const short* __restrict__ Wp0, const short* __restrict__ lWp0,
    const float* __restrict__ as0, const float* __restrict__ ad0,
    __hip_bfloat16* __restrict__ h0, __hip_bfloat16* __restrict__ skipb,
    float* __restrict__ a0s, float* __restrict__ a0d, int N) {
    __shared__ short tile[4][16 * TSTR];
    int wv = threadIdx.x >> 6, lane = threadIdx.x & 63;
    int rowbase = blockIdx.x * 64 + wv * 16;
    int m = lane & 15, q = lane >> 4;
    int arow = rowbase + m; if (arow >= N) arow = N - 1;
    bf8_t a[4];
    #pragma unroll
    for (int kb = 0; kb < 4; kb++) {
        const float4* px = (const float4*)(x + (size_t)arow * 128 + kb * 32 + q * 8);
        float4 lo = px[0], hi = px[1];
        bf8_t f;
        f[0] = f2bf(lo.x); f[1] = f2bf(lo.y); f[2] = f2bf(lo.z); f[3] = f2bf(lo.w);
        f[4] = f2bf(hi.x); f[5] = f2bf(hi.y); f[6] = f2bf(hi.z); f[7] = f2bf(hi.w);
        a[kb] = f;
    }
    float sacc[4][4], dacc[4][4];
    #pragma unroll
    for (int h = 0; h < 4; h++)
        #pragma unroll
        for (int r = 0; r < 4; r++) { sacc[h][r] = 0.f; dacc[h][r] = 0.f; }
    short* tl = tile[wv];
    int r4 = lane >> 2, qt = lane & 3;         // drain mapping: row, 64B quarter
    int drow = rowbase + r4;

    // phase 1: h0 (cts 0..7) + att accumulation
    #pragma unroll
    for (int ct = 0; ct < 8; ct++) {
        f4_t acc = {0.f, 0.f, 0.f, 0.f};
        #pragma unroll
        for (int kb = 0; kb < 4; kb++) {
            bf8_t b = *(const bf8_t*)(Wp0 + (((ct * 4 + kb) * 64 + lane) << 3));
            acc = __builtin_amdgcn_mfma_f32_16x16x32_bf16(a[kb], b, acc, 0, 0, 0);
        }
        int hd = ct >> 1;
        float ws = as0[ct * 16 + m], wd = ad0[ct * 16 + m];
        #pragma unroll
        for (int r = 0; r < 4; r++) {
            sacc[hd][r] += acc[r] * ws;
            dacc[hd][r] += acc[r] * wd;
            tl[(q * 4 + r) * TSTR + ct * 16 + m] = f2bf(acc[r]);
        }
    }
    if (drow < N) {
        short* dst = (short*)h0 + (size_t)drow * 128 + qt * 32;
        const short* srcp = tl + r4 * TSTR + qt * 32;
        #pragma unroll
        for (int s = 0; s < 4; s++)
            *(uint4*)(dst + s * 8) = *(const uint4*)(srcp + s * 8);
    }

    // phase 2: skip (cts 8..15) -> same tile, drain to skipb
    #pragma unroll
    for (int ct = 0; ct < 8; ct++) {
        f4_t acc = {0.f, 0.f, 0.f, 0.f};
        #pragma unroll
        for (int kb = 0; kb < 4; kb++) {
            bf8_t b = *(const bf8_t*)(lWp0 + (((ct * 4 + kb) * 64 + lane) << 3));
            acc = __builtin_amdgcn_mfma_f32_16x16x32_bf16(a[kb], b, acc, 0, 0, 0);
        }
        #pragma unroll
        for (int r = 0; r < 4; r++)
            tl[(q * 4 + r) * TSTR + ct * 16 + m] = f2bf(acc[r]);
    }
    if (drow < N) {
        short* dst = (short*)skipb + (size_t)drow * 128 + qt * 32;
        const short* srcp = tl + r4 * TSTR + qt * 32;
        #pragma unroll
        for (int s = 0; s < 4; s++)
            *(uint4*)(dst + s * 8) = *(const uint4*)(srcp + s * 8);
    }

    // att logits: reduce over the 16 m-lanes
    #pragma unroll
    for (int h = 0; h < 4; h++)
        #pragma unroll
        for (int r = 0; r < 4; r++) {
            float s = sacc[h][r], d = dacc[h][r];
            #pragma unroll
            for (int off = 1; off < 16; off <<= 1) {
                s += __shfl_xor(s, off);
                d += __shfl_xor(d, off);
            }
            sacc[h][r] = s; dacc[h][r] = d;
        }
    if (m < 4) {
        #pragma unroll
        for (int r = 0; r < 4; r++) {
            int row = rowbase + q * 4 + r;
            if (row < N) {
                float sv = (m == 0) ? sacc[0][r] : (m == 1) ? sacc[1][r]
                         : (m == 2) ? sacc[2][r] : sacc[3][r];
                float dv = (m == 0) ? dacc[0][r] : (m == 1) ? dacc[1][r]
                         : (m == 2) ? dacc[2][r] : dacc[3][r];
                a0s[row * 4 + m] = sv;
                a0d[row * 4 + m] = dv;
            }
        }
    }
}

// ---------------- GEMM1 + fused att1 ----------------

__global__ __launch_bounds__(256) void k_gemm1(
    const __hip_bfloat16* __restrict__ hin,
    const short* __restrict__ Wp1, const short* __restrict__ lWp1,
    const float* __restrict__ as1, const float* __restrict__ ad1,
    __hip_bfloat16* __restrict__ h1, float* __restrict__ skipb /* = d_out */,
    float* __restrict__ a1s, float* __restrict__ a1d, int N) {
    __shared__ short th[4][16 * 40];           // h1 tile (stride 40 shorts, 80B)
    __shared__ float ts[4][16 * 36];           // skip tile (stride 36 floats, 144B)
    int wv = threadIdx.x >> 6, lane = threadIdx.x & 63;
    int rowbase = blockIdx.x * 64 + wv * 16;
    int m = lane & 15, q = lane >> 4;
    int arow = rowbase + m; if (arow >= N) arow = N - 1;
    const short* xs = (const short*)hin;
    bf8_t a[4];
    #pragma unroll
    for (int kb = 0; kb < 4; kb++)
        a[kb] = *(const bf8_t*)(xs + (size_t)arow * 128 + kb * 32 + q * 8);
    float sacc[4], dacc[4];
    #pragma unroll
    for (int r = 0; r < 4; r++) { sacc[r] = 0.f; dacc[r] = 0.f; }
    short* tlh = th[wv];
    float* tls = ts[wv];
    int r4 = lane >> 2, qt = lane & 3;
    int drow = rowbase + r4;

    #pragma unroll
    for (int ct = 0; ct < 2; ct++) {           // h1 + att
        f4_t acc = {0.f, 0.f, 0.f, 0.f};
        #pragma unroll
        for (int kb = 0; kb < 4; kb++) {
            bf8_t b = *(const bf8_t*)(Wp1 + (((ct * 4 + kb) * 64 + lane) << 3));
            acc = __builtin_amdgcn_mfma_f32_16x16x32_bf16(a[kb], b, acc, 0, 0, 0);
        }
        float ws = as1[ct * 16 + m], wd = ad1[ct * 16 + m];
        #pragma unroll
        for (int r = 0; r < 4; r++) {
            sacc[r] += acc[r] * ws;
            dacc[r] += acc[r] * wd;
            tlh[(q * 4 + r) * 40 + ct * 16 + m] = f2bf(acc[r]);
        }
    }
    #pragma unroll
    for (int ct = 0; ct < 2; ct++) {           // skip (f32)
        f4_t acc = {0.f, 0.f, 0.f, 0.f};
        #pragma unroll
        for (int kb = 0; kb < 4; kb++) {
            bf8_t b = *(const bf8_t*)(lWp1 + (((ct * 4 + kb) * 64 + lane) << 3));
            acc = __builtin_amdgcn_mfma_f32_16x16x32_bf16(a[kb], b, acc, 0, 0, 0);
        }
        #pragma unroll
        for (int r = 0; r < 4; r++)
            tls[(q * 4 + r) * 36 + ct * 16 + m] = acc[r];
    }
    if (drow < N) {
        // h1: 16 rows x 64B -> each lane one 16B chunk
        *(uint4*)((short*)h1 + (size_t)drow * 32 + qt * 8) =
            *(const uint4*)(tlh + r4 * 40 + qt * 8);
        // skip: 16 rows x 128B -> each lane one 32B chunk
        float* dst = skipb + (size_t)drow * 32 + qt * 8;
        const float* srcp = tls + r4 * 36 + qt * 8;
        *(uint4*)(dst) = *(const uint4*)(srcp);
        *(uint4*)(dst + 4) = *(const uint4*)(srcp + 4);
    }
    #pragma unroll
    for (int r = 0; r < 4; r++) {
        float s = sacc[r], d = dacc[r];
        #pragma unroll
        for (int off = 1; off < 16; off <<= 1) {
            s += __shfl_xor(s, off);
            d += __shfl_xor(d, off);
        }
        if (m == 0) {
            int row = rowbase + q * 4 + r;
            if (row < N) { a1s[row] = s; a1d[row] = d; }
        }
    }
}

// ---------------- aggregation: 16-lane edge groups, 1 wave/node ----------------

__global__ __launch_bounds__(256) void k_agg0(
    const int* __restrict__ rowstart, const unsigned short* __restrict__ esrc,
    const unsigned int* __restrict__ h0u,              // row = 64 uints (bf16x2)
    const float* __restrict__ a0s, const float* __restrict__ a0d,
    const float* __restrict__ bc0,                     // bias0+linb0 [128]
    unsigned int* __restrict__ h1in_u,                 // in: skip0 bf16, out: ELU
    int n) {
    int node = (blockIdx.x * 256 + threadIdx.x) >> 6;
    int lane = threadIdx.x & 63;
    if (node >= n) return;
    int g = lane >> 4, t = lane & 15, hd = t >> 2;
    float ad = a0d[node * 4 + hd];
    int s0 = rowstart[node], s1 = rowstart[node + 1];
    float den = 0.f;
    float acc[8];
    #pragma unroll
    for (int k = 0; k < 8; k++) acc[k] = 0.f;
    int i = s0 + g;
    for (; i + 4 < s1; i += 8) {               // 2 edges/group/iter = 8/wave
        int sA = esrc[i], sB = esrc[i + 4];
        float eA = a0s[sA * 4 + hd] + ad;
        float eB = a0s[sB * 4 + hd] + ad;
        uint4 pA = *(const uint4*)(h0u + (size_t)sA * 64 + t * 4);
        uint4 pB = *(const uint4*)(h0u + (size_t)sB * 64 + t * 4);
        float wA = lrexp(eA), wB = lrexp(eB);
        den += wA + wB;
        acc[0] += wA * blo(pA.x) + wB * blo(pB.x);
        acc[1] += wA * bhi(pA.x) + wB * bhi(pB.x);
        acc[2] += wA * blo(pA.y) + wB * blo(pB.y);
        acc[3] += wA * bhi(pA.y) + wB * bhi(pB.y);
        acc[4] += wA * blo(pA.z) + wB * blo(pB.z);
        acc[5] += wA * bhi(pA.z) + wB * bhi(pB.z);
        acc[6] += wA * blo(pA.w) + wB * blo(pB.w);
        acc[7] += wA * bhi(pA.w) + wB * bhi(pB.w);
    }
    for (; i < s1; i += 4) {
        int s = esrc[i];
        float wv = lrexp(a0s[s * 4 + hd] + ad);
        uint4 p = *(const uint4*)(h0u + (size_t)s * 64 + t * 4);
        den += wv;
        acc[0] += wv * blo(p.x); acc[1] += wv * bhi(p.x);
        acc[2] += wv * blo(p.y); acc[3] += wv * bhi(p.y);
        acc[4] += wv * blo(p.z); acc[5] += wv * bhi(p.z);
        acc[6] += wv * blo(p.w); acc[7] += wv * bhi(p.w);
    }
    #pragma unroll
    for (int k = 0; k < 8; k++) {
        acc[k] += __shfl_xor(acc[k], 16);
        acc[k] += __shfl_xor(acc[k], 32);
    }
    den += __shfl_xor(den, 16);
    den += __shfl_xor(den, 32);
    if (g == 0) {
        float inv = 1.0f / (den + 1e-16f);
        uint4 sp = *(const uint4*)(h1in_u + (size_t)node * 64 + t * 4); // skip0
        int c0 = t * 8;
        float o[8];
        o[0] = acc[0] * inv + blo(sp.x) + bc0[c0 + 0];
        o[1] = acc[1] * inv + bhi(sp.x) + bc0[c0 + 1];
        o[2] = acc[2] * inv + blo(sp.y) + bc0[c0 + 2];
        o[3] = acc[3] * inv + bhi(sp.y) + bc0[c0 + 3];
        o[4] = acc[4] * inv + blo(sp.z) + bc0[c0 + 4];
        o[5] = acc[5] * inv + bhi(sp.z) + bc0[c0 + 5];
        o[6] = acc[6] * inv + blo(sp.w) + bc0[c0 + 6];
        o[7] = acc[7] * inv + bhi(sp.w) + bc0[c0 + 7];
        #pragma unroll
        for (int k = 0; k < 8; k++)
            o[k] = (o[k] > 0.f) ? o[k] : (__expf(o[k]) - 1.f);  // ELU
        uint4 res;
        res.x = (unsigned int)(unsigned short)f2bf(o[0]) | ((unsigned int)(unsigned short)f2bf(o[1]) << 16);
        res.y = (unsigned int)(unsigned short)f2bf(o[2]) | ((unsigned int)(unsigned short)f2bf(o[3]) << 16);
        res.z = (unsigned int)(unsigned short)f2bf(o[4]) | ((unsigned int)(unsigned short)f2bf(o[5]) << 16);
        res.w = (unsigned int)(unsigned short)f2bf(o[6]) | ((unsigned int)(unsigned short)f2bf(o[7]) << 16);
        *(uint4*)(h1in_u + (size_t)node * 64 + t * 4) = res;
    }
}

__global__ __launch_bounds__(256) void k_agg1(
    const int* __restrict__ rowstart, const unsigned short* __restrict__ esrc,
    const __hip_bfloat16* __restrict__ h1,
    const float* __restrict__ a1s, const float* __restrict__ a1d,
    const float* __restrict__ bc1,                     // bias1+linb1 [32]
    float* __restrict__ out, int n) {
    int node = (blockIdx.x * 256 + threadIdx.x) >> 6;
    int lane = threadIdx.x & 63;
    if (node >= n) return;
    int g = lane >> 4, t = lane & 15;
    float ad = a1d[node];
    int s0 = rowstart[node], s1 = rowstart[node + 1];
    const unsigned int* h1w = (const unsigned int*)h1;  // row = 16 uints
    float den = 0.f, acc0 = 0.f, acc1 = 0.f;
    int i = s0 + g;
    for (; i + 4 < s1; i += 8) {
        int sA = esrc[i], sB = esrc[i + 4];
        float eA = a1s[sA] + ad, eB = a1s[sB] + ad;
        unsigned int pA = h1w[(size_t)sA * 16 + t];
        unsigned int pB = h1w[(size_t)sB * 16 + t];
        float wA = lrexp(eA), wB = lrexp(eB);
        den += wA + wB;
        acc0 += wA * blo(pA) + wB * blo(pB);
        acc1 += wA * bhi(pA) + wB * bhi(pB);
    }
    for (; i < s1; i += 4) {
        int s = esrc[i];
        float wv = lrexp(a1s[s] + ad);
        unsigned int p = h1w[(size_t)s * 16 + t];
        den += wv; acc0 += wv * blo(p); acc1 += wv * bhi(p);
    }
    acc0 += __shfl_xor(acc0, 16); acc0 += __shfl_xor(acc0, 32);
    acc1 += __shfl_xor(acc1, 16); acc1 += __shfl_xor(acc1, 32);
    den  += __shfl_xor(den, 16);  den  += __shfl_xor(den, 32);
    if (g == 0) {
        float inv = 1.0f / (den + 1e-16f);
        int c0 = t * 2;
        size_t idx = (size_t)node * 32 + c0;
        float2 sk = *(const float2*)(out + idx);     // skip1
        float2 r;
        r.x = acc0 * inv + sk.x + bc1[c0];
        r.y = acc1 * inv + sk.y + bc1[c0 + 1];
        *(float2*)(out + idx) = r;
    }
}

// ---------------- launch ----------------

extern "C" void kernel_launch(void* const* d_in, const int* in_sizes, int n_in,
                              void* d_out, int out_size, void* d_ws, size_t ws_size,
                              hipStream_t stream) {
    const float* x   = (const float*)d_in[0];
    const int*   ei  = (const int*)d_in[1];
    const float* W0  = (const float*)d_in[2];
    const float* as0 = (const float*)d_in[3];
    const float* ad0 = (const float*)d_in[4];
    const float* b0  = (const float*)d_in[5];
    const float* lW0 = (const float*)d_in[6];
    const float* lb0 = (const float*)d_in[7];
    const float* W1  = (const float*)d_in[8];
    const float* as1 = (const float*)d_in[9];
    const float* ad1 = (const float*)d_in[10];
    const float* b1  = (const float*)d_in[11];
    const float* lW1 = (const float*)d_in[12];
    const float* lb1 = (const float*)d_in[13];
    float* out = (float*)d_out;

    const int N = in_sizes[0] / 128;
    const int E = in_sizes[1] / 2;
    const int T = E + N;
    const int NB = (N + 1023) / 1024;

    // workspace carve-up (256B aligned), ~29.5 MB
    char* w = (char*)d_ws;
    auto alloc = [&](size_t bytes) -> char* {
        char* p = w; w += (bytes + 255) / 256 * 256; return p;
    };
    int* rowstart  = (int*)alloc((size_t)(N + 1) * 4);
    int* cnt       = (int*)alloc((size_t)N * 4);          // deg, then fill-cursor
    int* bsum      = (int*)alloc(64 * 4);
    int* bcar      = (int*)alloc(64 * 4);
    unsigned short* esrc = (unsigned short*)alloc((size_t)T * 2);
    float* aS      = (float*)alloc((size_t)N * 4 * 4);    // layer0 [N,4]; layer1 [N]
    float* aD      = (float*)alloc((size_t)N * 4 * 4);
    __hip_bfloat16* hbuf = (__hip_bfloat16*)alloc((size_t)N * 128 * 2); // h0 / h1
    __hip_bfloat16* h1in = (__hip_bfloat16*)alloc((size_t)N * 128 * 2); // skip0 -> ELU
    short* Wp0  = (short*)alloc(16384 * 2);
    short* lWp0 = (short*)alloc(16384 * 2);
    short* Wp1  = (short*)alloc(4096 * 2);
    short* lWp1 = (short*)alloc(4096 * 2);
    float* bc0  = (float*)alloc(128 * 4);
    float* bc1  = (float*)alloc(32 * 4);

    // init (zero counters + packed weights + combined biases), then CSR build
    k_init<<<(N + 255) / 256, 256, 0, stream>>>(W0, lW0, W1, lW1, b0, lb0, b1, lb1,
                                                Wp0, lWp0, Wp1, lWp1, bc0, bc1, cnt, N);
    k_count<<<(T + 255) / 256, 256, 0, stream>>>(ei, cnt, E, N);
    k_scan1<<<NB, 1024, 0, stream>>>(cnt, rowstart, bsum, N);
    k_scan2<<<1, 64, 0, stream>>>(bsum, bcar, rowstart, NB, N);
    k_scan3<<<NB, 1024, 0, stream>>>(rowstart, bcar, cnt, N);
    k_fill<<<(T + 255) / 256, 256, 0, stream>>>(ei, cnt, esrc, E, N);

    // layer 0 (att fused into gemm)
    k_gemm0<<<(N + 63) / 64, 256, 0, stream>>>(x, Wp0, lWp0, as0, ad0,
                                               hbuf, h1in, aS, aD, N);
    k_agg0<<<(N + 3) / 4, 256, 0, stream>>>(rowstart, esrc, (const unsigned int*)hbuf,
                                            aS, aD, bc0, (unsigned int*)h1in, N);
    // layer 1 (h1 reuses hbuf; skip1 lives in d_out f32; att fused)
    k_gemm1<<<(N + 63) / 64, 256, 0, stream>>>(h1in, Wp1, lWp1, as1, ad1,
                                               hbuf, out, aS, aD, N);
    k_agg1<<<(N + 3) / 4, 256, 0, stream>>>(rowstart, esrc, hbuf, aS, aD,
                                            bc1, out, N);
}

// Round 11
// 225.884 us; speedup vs baseline: 1.3069x; 1.2480x over previous
//
#include <hip/hip_runtime.h>
#include <hip/hip_bf16.h>

// GATNet 2-layer GAT, N=50000, E=800000 (+N self loops). f32 in/out, bf16 MFMA.
// Round-11: CSR build replaced by two-level bucket sort (r10 k_fill showed
// 42MB HBM writeback from random 2B scatter stores; k_count's 850K global
// atomics also eliminated). k_bucket: per-block LDS-ranked runs into 256-node
// buckets (packed dst<<16|src). k_fill2: per-bucket LDS histogram+scan ->
// rowstart slice + esrc fill, all writes confined to one L2. gemm/agg = r10.

typedef __attribute__((ext_vector_type(8))) short bf8_t;   // 8 x bf16 (4 VGPRs)
typedef __attribute__((ext_vector_type(4))) float f4_t;

#define NBUCK 256      // bucket table size (used buckets = (N+255)>>8 = 196)
#define BCAP  8192     // per-bucket capacity (expected ~4352, uniform random)

__device__ inline short f2bf(float f) {
    return (short)__builtin_bit_cast(unsigned short, __float2bfloat16(f));
}
__device__ inline float blo(unsigned int p) { return __uint_as_float(p << 16); }
__device__ inline float bhi(unsigned int p) { return __uint_as_float(p & 0xffff0000u); }
__device__ inline float lrexp(float e) {
    e = (e > 0.f) ? e : 0.2f * e;          // leaky_relu(0.2); |e|<~12 -> exp safe
    return __expf(e);
}

// ---- init: bucket cursors + weights -> bf16 packed in MFMA-fragment order ----
// Wp[((ct*4+kb)*64 + lane)*8 + j] = W[ct*16 + (lane&15)][kb*32 + (lane>>4)*8 + j]
__global__ void k_init(const float* __restrict__ W0, const float* __restrict__ lW0,
                       const float* __restrict__ W1, const float* __restrict__ lW1,
                       const float* __restrict__ b0, const float* __restrict__ lb0,
                       const float* __restrict__ b1, const float* __restrict__ lb1,
                       short* __restrict__ Wp0, short* __restrict__ lWp0,
                       short* __restrict__ Wp1, short* __restrict__ lWp1,
                       float* __restrict__ bc0, float* __restrict__ bc1,
                       int* __restrict__ gcur) {
    int i = blockIdx.x * blockDim.x + threadIdx.x;
    if (i < NBUCK) gcur[i] = i * BCAP;
    if (i < 16384) {
        int j = i & 7, lane = (i >> 3) & 63, kc = i >> 9;
        int kb = kc & 3, ct = kc >> 2;                  // ct 0..7
        int src = (ct * 16 + (lane & 15)) * 128 + kb * 32 + (lane >> 4) * 8 + j;
        Wp0[i]  = f2bf(W0[src]);
        lWp0[i] = f2bf(lW0[src]);
    }
    if (i < 4096) {
        int j = i & 7, lane = (i >> 3) & 63, kc = i >> 9;
        int kb = kc & 3, ct = kc >> 2;                  // ct 0..1
        int src = (ct * 16 + (lane & 15)) * 128 + kb * 32 + (lane >> 4) * 8 + j;
        Wp1[i]  = f2bf(W1[src]);
        lWp1[i] = f2bf(lW1[src]);
    }
    if (i < 128) bc0[i] = b0[i] + lb0[i];
    else if (i < 160) bc1[i - 128] = b1[i - 128] + lb1[i - 128];
}

// ---------------- CSR build: two-level bucket sort ----------------

// 2048 edges/block. LDS histogram assigns per-edge local ranks; one global
// atomic per (block,bucket) reserves a contiguous run -> semi-coalesced writes.
__global__ __launch_bounds__(256) void k_bucket(
    const int* __restrict__ ei, int* __restrict__ gcur,
    unsigned int* __restrict__ bucketed, int E, int T) {
    __shared__ int hist[NBUCK];
    __shared__ int gbase[NBUCK];
    int tid = threadIdx.x;
    hist[tid] = 0;
    __syncthreads();
    int base = blockIdx.x * 2048;
    unsigned int pk[8]; int rk[8]; int bk[8];
    #pragma unroll
    for (int j = 0; j < 8; j++) {
        int e = base + j * 256 + tid;
        if (e < T) {
            int src, dst;
            if (e < E) { src = ei[e]; dst = ei[E + e]; }
            else       { src = e - E; dst = src; }          // self-loops
            int b = dst >> 8;
            pk[j] = ((unsigned int)dst << 16) | (unsigned int)src;
            bk[j] = b;
            rk[j] = atomicAdd(&hist[b], 1);
        } else bk[j] = -1;
    }
    __syncthreads();
    int h = hist[tid];
    if (h > 0) gbase[tid] = atomicAdd(&gcur[tid], h);
    __syncthreads();
    #pragma unroll
    for (int j = 0; j < 8; j++)
        if (bk[j] >= 0)
            bucketed[gbase[bk[j]] + rk[j]] = pk[j];
}

// exclusive scan of bucket totals -> bucket bases; grand total -> rowstart[N]
__global__ void k_bscan(const int* __restrict__ gcur, int* __restrict__ bbase,
                        int* __restrict__ rowstart, int n) {
    __shared__ int buf[NBUCK];
    int t = threadIdx.x;
    int v = gcur[t] - t * BCAP;
    buf[t] = v;
    __syncthreads();
    for (int off = 1; off < NBUCK; off <<= 1) {
        int tv = (t >= off) ? buf[t - off] : 0;
        __syncthreads();
        buf[t] += tv;
        __syncthreads();
    }
    bbase[t] = buf[t] - v;                 // exclusive
    if (t == NBUCK - 1) rowstart[n] = buf[t];
}

// one block per bucket: LDS histogram -> local scan -> rowstart slice (coalesced)
// + esrc fill via LDS cursors; all stores land in one ~9KB window (L2-local).
__global__ __launch_bounds__(256) void k_fill2(
    const unsigned int* __restrict__ bucketed, const int* __restrict__ gcur,
    const int* __restrict__ bbase, int* __restrict__ rowstart,
    unsigned short* __restrict__ esrc, int N) {
    __shared__ int hist[256];
    __shared__ int incl[256];
    int b = blockIdx.x, t = threadIdx.x;
    int nodebase = b << 8;
    int used = gcur[b] - b * BCAP;
    const unsigned int* bk = bucketed + (size_t)b * BCAP;
    hist[t] = 0;
    __syncthreads();
    for (int i = t; i < used; i += 256)
        atomicAdd(&hist[(bk[i] >> 16) - nodebase], 1);
    __syncthreads();
    int v = hist[t];
    incl[t] = v;
    __syncthreads();
    for (int off = 1; off < 256; off <<= 1) {
        int tv = (t >= off) ? incl[t - off] : 0;
        __syncthreads();
        incl[t] += tv;
        __syncthreads();
    }
    int myexcl = incl[t] - v;
    int rbase = bbase[b];
    int node = nodebase + t;
    if (node < N) rowstart[node] = rbase + myexcl;
    __syncthreads();
    hist[t] = myexcl;                      // reuse as fill cursor
    __syncthreads();
    for (int i = t; i < used; i += 256) {
        unsigned int p = bk[i];
        int pos = atomicAdd(&hist[(p >> 16) - nodebase], 1);
        esrc[rbase + pos] = (unsigned short)(p & 0xffffu);
    }
}

// ---------------- GEMM0 + fused att0 ----------------
// A-frag: lane holds A[m=lane&15][k=(lane>>4)*8+j]; B from packed tables.
// C/D  : col=lane&15, row=(lane>>4)*4+reg  (m89-verified)
// Output staged per-wave in LDS, drained with coalesced dwordx4 stores.

#define TSTR 136   // LDS tile row stride in shorts (272B, 16B-aligned)

__global__ __launch_bounds__(256) void k_gemm0(
    const float* __restrict__ x,
    const short* __restrict__ Wp0, const short* __restrict__ lWp0,
    const float* __restrict__ as0, const float* __restrict__ ad0,
    __hip_bfloat16* __restrict__ h0, __hip_bfloat16* __restrict__ skipb,
    float* __restrict__ a0s, float* __restrict__ a0d, int N) {
    __shared__ short tile[4][16 * TSTR];
    int wv = threadIdx.x >> 6, lane = threadIdx.x & 63;
    int rowbase = blockIdx.x * 64 + wv * 16;
    int m = lane & 15, q = lane >> 4;
    int arow = rowbase + m; if (arow >= N) arow = N - 1;
    bf8_t a[4];
    #pragma unroll
    for (int kb = 0; kb < 4; kb++) {
        const float4* px = (const float4*)(x + (size_t)arow * 128 + kb * 32 + q * 8);
        float4 lo = px[0], hi = px[1];
        bf8_t f;
        f[0] = f2bf(lo.x); f[1] = f2bf(lo.y); f[2] = f2bf(lo.z); f[3] = f2bf(lo.w);
        f[4] = f2bf(hi.x); f[5] = f2bf(hi.y); f[6] = f2bf(hi.z); f[7] = f2bf(hi.w);
        a[kb] = f;
    }
    float sacc[4][4], dacc[4][4];
    #pragma unroll
    for (int h = 0; h < 4; h++)
        #pragma unroll
        for (int r = 0; r < 4; r++) { sacc[h][r] = 0.f; dacc[h][r] = 0.f; }
    short* tl = tile[wv];
    int r4 = lane >> 2, qt = lane & 3;         // drain mapping: row, 64B quarter
    int drow = rowbase + r4;

    // phase 1: h0 (cts 0..7) + att accumulation
    #pragma unroll
    for (int ct = 0; ct < 8; ct++) {
        f4_t acc = {0.f, 0.f, 0.f, 0.f};
        #pragma unroll
        for (int kb = 0; kb < 4; kb++) {
            bf8_t b = *(const bf8_t*)(Wp0 + (((ct * 4 + kb) * 64 + lane) << 3));
            acc = __builtin_amdgcn_mfma_f32_16x16x32_bf16(a[kb], b, acc, 0, 0, 0);
        }
        int hd = ct >> 1;
        float ws = as0[ct * 16 + m], wd = ad0[ct * 16 + m];
        #pragma unroll
        for (int r = 0; r < 4; r++) {
            sacc[hd][r] += acc[r] * ws;
            dacc[hd][r] += acc[r] * wd;
            tl[(q * 4 + r) * TSTR + ct * 16 + m] = f2bf(acc[r]);
        }
    }
    if (drow < N) {
        short* dst = (short*)h0 + (size_t)drow * 128 + qt * 32;
        const short* srcp = tl + r4 * TSTR + qt * 32;
        #pragma unroll
        for (int s = 0; s < 4; s++)
            *(uint4*)(dst + s * 8) = *(const uint4*)(srcp + s * 8);
    }

    // phase 2: skip (cts 8..15) -> same tile, drain to skipb
    #pragma unroll
    for (int ct = 0; ct < 8; ct++) {
        f4_t acc = {0.f, 0.f, 0.f, 0.f};
        #pragma unroll
        for (int kb = 0; kb < 4; kb++) {
            bf8_t b = *(const bf8_t*)(lWp0 + (((ct * 4 + kb) * 64 + lane) << 3));
            acc = __builtin_amdgcn_mfma_f32_16x16x32_bf16(a[kb], b, acc, 0, 0, 0);
        }
        #pragma unroll
        for (int r = 0; r < 4; r++)
            tl[(q * 4 + r) * TSTR + ct * 16 + m] = f2bf(acc[r]);
    }
    if (drow < N) {
        short* dst = (short*)skipb + (size_t)drow * 128 + qt * 32;
        const short* srcp = tl + r4 * TSTR + qt * 32;
        #pragma unroll
        for (int s = 0; s < 4; s++)
            *(uint4*)(dst + s * 8) = *(const uint4*)(srcp + s * 8);
    }

    // att logits: reduce over the 16 m-lanes
    #pragma unroll
    for (int h = 0; h < 4; h++)
        #pragma unroll
        for (int r = 0; r < 4; r++) {
            float s = sacc[h][r], d = dacc[h][r];
            #pragma unroll
            for (int off = 1; off < 16; off <<= 1) {
                s += __shfl_xor(s, off);
                d += __shfl_xor(d, off);
            }
            sacc[h][r] = s; dacc[h][r] = d;
        }
    if (m < 4) {
        #pragma unroll
        for (int r = 0; r < 4; r++) {
            int row = rowbase + q * 4 + r;
            if (row < N) {
                float sv = (m == 0) ? sacc[0][r] : (m == 1) ? sacc[1][r]
                         : (m == 2) ? sacc[2][r] : sacc[3][r];
                float dv = (m == 0) ? dacc[0][r] : (m == 1) ? dacc[1][r]
                         : (m == 2) ? dacc[2][r] : dacc[3][r];
                a0s[row * 4 + m] = sv;
                a0d[row * 4 + m] = dv;
            }
        }
    }
}

// ---------------- GEMM1 + fused att1 ----------------

__global__ __launch_bounds__(256) void k_gemm1(
    const __hip_bfloat16* __restrict__ hin,
    const short* __restrict__ Wp1, const short* __restrict__ lWp1,
    const float* __restrict__ as1, const float* __restrict__ ad1,
    __hip_bfloat16* __restrict__ h1, float* __restrict__ skipb /* = d_out */,
    float* __restrict__ a1s, float* __restrict__ a1d, int N) {
    __shared__ short th[4][16 * 40];           // h1 tile (stride 40 shorts)
    __shared__ float ts[4][16 * 36];           // skip tile (stride 36 floats)
    int wv = threadIdx.x >> 6, lane = threadIdx.x & 63;
    int rowbase = blockIdx.x * 64 + wv * 16;
    int m = lane & 15, q = lane >> 4;
    int arow = rowbase + m; if (arow >= N) arow = N - 1;
    const short* xs = (const short*)hin;
    bf8_t a[4];
    #pragma unroll
    for (int kb = 0; kb < 4; kb++)
        a[kb] = *(const bf8_t*)(xs + (size_t)arow * 128 + kb * 32 + q * 8);
    float sacc[4], dacc[4];
    #pragma unroll
    for (int r = 0; r < 4; r++) { sacc[r] = 0.f; dacc[r] = 0.f; }
    short* tlh = th[wv];
    float* tls = ts[wv];
    int r4 = lane >> 2, qt = lane & 3;
    int drow = rowbase + r4;

    #pragma unroll
    for (int ct = 0; ct < 2; ct++) {           // h1 + att
        f4_t acc = {0.f, 0.f, 0.f, 0.f};
        #pragma unroll
        for (int kb = 0; kb < 4; kb++) {
            bf8_t b = *(const bf8_t*)(Wp1 + (((ct * 4 + kb) * 64 + lane) << 3));
            acc = __builtin_amdgcn_mfma_f32_16x16x32_bf16(a[kb], b, acc, 0, 0, 0);
        }
        float ws = as1[ct * 16 + m], wd = ad1[ct * 16 + m];
        #pragma unroll
        for (int r = 0; r < 4; r++) {
            sacc[r] += acc[r] * ws;
            dacc[r] += acc[r] * wd;
            tlh[(q * 4 + r) * 40 + ct * 16 + m] = f2bf(acc[r]);
        }
    }
    #pragma unroll
    for (int ct = 0; ct < 2; ct++) {           // skip (f32)
        f4_t acc = {0.f, 0.f, 0.f, 0.f};
        #pragma unroll
        for (int kb = 0; kb < 4; kb++) {
            bf8_t b = *(const bf8_t*)(lWp1 + (((ct * 4 + kb) * 64 + lane) << 3));
            acc = __builtin_amdgcn_mfma_f32_16x16x32_bf16(a[kb], b, acc, 0, 0, 0);
        }
        #pragma unroll
        for (int r = 0; r < 4; r++)
            tls[(q * 4 + r) * 36 + ct * 16 + m] = acc[r];
    }
    if (drow < N) {
        *(uint4*)((short*)h1 + (size_t)drow * 32 + qt * 8) =
            *(const uint4*)(tlh + r4 * 40 + qt * 8);
        float* dst = skipb + (size_t)drow * 32 + qt * 8;
        const float* srcp = tls + r4 * 36 + qt * 8;
        *(uint4*)(dst) = *(const uint4*)(srcp);
        *(uint4*)(dst + 4) = *(const uint4*)(srcp + 4);
    }
    #pragma unroll
    for (int r = 0; r < 4; r++) {
        float s = sacc[r], d = dacc[r];
        #pragma unroll
        for (int off = 1; off < 16; off <<= 1) {
            s += __shfl_xor(s, off);
            d += __shfl_xor(d, off);
        }
        if (m == 0) {
            int row = rowbase + q * 4 + r;
            if (row < N) { a1s[row] = s; a1d[row] = d; }
        }
    }
}

// ---------------- aggregation: 16-lane edge groups, 1 wave/node ----------------

__global__ __launch_bounds__(256) void k_agg0(
    const int* __restrict__ rowstart, const unsigned short* __restrict__ esrc,
    const unsigned int* __restrict__ h0u,              // row = 64 uints (bf16x2)
    const float* __restrict__ a0s, const float* __restrict__ a0d,
    const float* __restrict__ bc0,                     // bias0+linb0 [128]
    unsigned int* __restrict__ h1in_u,                 // in: skip0 bf16, out: ELU
    int n) {
    int node = (blockIdx.x * 256 + threadIdx.x) >> 6;
    int lane = threadIdx.x & 63;
    if (node >= n) return;
    int g = lane >> 4, t = lane & 15, hd = t >> 2;
    float ad = a0d[node * 4 + hd];
    int s0 = rowstart[node], s1 = rowstart[node + 1];
    float den = 0.f;
    float acc[8];
    #pragma unroll
    for (int k = 0; k < 8; k++) acc[k] = 0.f;
    int i = s0 + g;
    for (; i + 4 < s1; i += 8) {               // 2 edges/group/iter = 8/wave
        int sA = esrc[i], sB = esrc[i + 4];
        float eA = a0s[sA * 4 + hd] + ad;
        float eB = a0s[sB * 4 + hd] + ad;
        uint4 pA = *(const uint4*)(h0u + (size_t)sA * 64 + t * 4);
        uint4 pB = *(const uint4*)(h0u + (size_t)sB * 64 + t * 4);
        float wA = lrexp(eA), wB = lrexp(eB);
        den += wA + wB;
        acc[0] += wA * blo(pA.x) + wB * blo(pB.x);
        acc[1] += wA * bhi(pA.x) + wB * bhi(pB.x);
        acc[2] += wA * blo(pA.y) + wB * blo(pB.y);
        acc[3] += wA * bhi(pA.y) + wB * bhi(pB.y);
        acc[4] += wA * blo(pA.z) + wB * blo(pB.z);
        acc[5] += wA * bhi(pA.z) + wB * bhi(pB.z);
        acc[6] += wA * blo(pA.w) + wB * blo(pB.w);
        acc[7] += wA * bhi(pA.w) + wB * bhi(pB.w);
    }
    for (; i < s1; i += 4) {
        int s = esrc[i];
        float wv = lrexp(a0s[s * 4 + hd] + ad);
        uint4 p = *(const uint4*)(h0u + (size_t)s * 64 + t * 4);
        den += wv;
        acc[0] += wv * blo(p.x); acc[1] += wv * bhi(p.x);
        acc[2] += wv * blo(p.y); acc[3] += wv * bhi(p.y);
        acc[4] += wv * blo(p.z); acc[5] += wv * bhi(p.z);
        acc[6] += wv * blo(p.w); acc[7] += wv * bhi(p.w);
    }
    #pragma unroll
    for (int k = 0; k < 8; k++) {
        acc[k] += __shfl_xor(acc[k], 16);
        acc[k] += __shfl_xor(acc[k], 32);
    }
    den += __shfl_xor(den, 16);
    den += __shfl_xor(den, 32);
    if (g == 0) {
        float inv = 1.0f / (den + 1e-16f);
        uint4 sp = *(const uint4*)(h1in_u + (size_t)node * 64 + t * 4); // skip0
        int c0 = t * 8;
        float o[8];
        o[0] = acc[0] * inv + blo(sp.x) + bc0[c0 + 0];
        o[1] = acc[1] * inv + bhi(sp.x) + bc0[c0 + 1];
        o[2] = acc[2] * inv + blo(sp.y) + bc0[c0 + 2];
        o[3] = acc[3] * inv + bhi(sp.y) + bc0[c0 + 3];
        o[4] = acc[4] * inv + blo(sp.z) + bc0[c0 + 4];
        o[5] = acc[5] * inv + bhi(sp.z) + bc0[c0 + 5];
        o[6] = acc[6] * inv + blo(sp.w) + bc0[c0 + 6];
        o[7] = acc[7] * inv + bhi(sp.w) + bc0[c0 + 7];
        #pragma unroll
        for (int k = 0; k < 8; k++)
            o[k] = (o[k] > 0.f) ? o[k] : (__expf(o[k]) - 1.f);  // ELU
        uint4 res;
        res.x = (unsigned int)(unsigned short)f2bf(o[0]) | ((unsigned int)(unsigned short)f2bf(o[1]) << 16);
        res.y = (unsigned int)(unsigned short)f2bf(o[2]) | ((unsigned int)(unsigned short)f2bf(o[3]) << 16);
        res.z = (unsigned int)(unsigned short)f2bf(o[4]) | ((unsigned int)(unsigned short)f2bf(o[5]) << 16);
        res.w = (unsigned int)(unsigned short)f2bf(o[6]) | ((unsigned int)(unsigned short)f2bf(o[7]) << 16);
        *(uint4*)(h1in_u + (size_t)node * 64 + t * 4) = res;
    }
}

__global__ __launch_bounds__(256) void k_agg1(
    const int* __restrict__ rowstart, const unsigned short* __restrict__ esrc,
    const __hip_bfloat16* __restrict__ h1,
    const float* __restrict__ a1s, const float* __restrict__ a1d,
    const float* __restrict__ bc1,                     // bias1+linb1 [32]
    float* __restrict__ out, int n) {
    int node = (blockIdx.x * 256 + threadIdx.x) >> 6;
    int lane = threadIdx.x & 63;
    if (node >= n) return;
    int g = lane >> 4, t = lane & 15;
    float ad = a1d[node];
    int s0 = rowstart[node], s1 = rowstart[node + 1];
    const unsigned int* h1w = (const unsigned int*)h1;  // row = 16 uints
    float den = 0.f, acc0 = 0.f, acc1 = 0.f;
    int i = s0 + g;
    for (; i + 4 < s1; i += 8) {
        int sA = esrc[i], sB = esrc[i + 4];
        float eA = a1s[sA] + ad, eB = a1s[sB] + ad;
        unsigned int pA = h1w[(size_t)sA * 16 + t];
        unsigned int pB = h1w[(size_t)sB * 16 + t];
        float wA = lrexp(eA), wB = lrexp(eB);
        den += wA + wB;
        acc0 += wA * blo(pA) + wB * blo(pB);
        acc1 += wA * bhi(pA) + wB * bhi(pB);
    }
    for (; i < s1; i += 4) {
        int s = esrc[i];
        float wv = lrexp(a1s[s] + ad);
        unsigned int p = h1w[(size_t)s * 16 + t];
        den += wv; acc0 += wv * blo(p); acc1 += wv * bhi(p);
    }
    acc0 += __shfl_xor(acc0, 16); acc0 += __shfl_xor(acc0, 32);
    acc1 += __shfl_xor(acc1, 16); acc1 += __shfl_xor(acc1, 32);
    den  += __shfl_xor(den, 16);  den  += __shfl_xor(den, 32);
    if (g == 0) {
        float inv = 1.0f / (den + 1e-16f);
        int c0 = t * 2;
        size_t idx = (size_t)node * 32 + c0;
        float2 sk = *(const float2*)(out + idx);     // skip1
        float2 r;
        r.x = acc0 * inv + sk.x + bc1[c0];
        r.y = acc1 * inv + sk.y + bc1[c0 + 1];
        *(float2*)(out + idx) = r;
    }
}

// ---------------- launch ----------------

extern "C" void kernel_launch(void* const* d_in, const int* in_sizes, int n_in,
                              void* d_out, int out_size, void* d_ws, size_t ws_size,
                              hipStream_t stream) {
    const float* x   = (const float*)d_in[0];
    const int*   ei  = (const int*)d_in[1];
    const float* W0  = (const float*)d_in[2];
    const float* as0 = (const float*)d_in[3];
    const float* ad0 = (const float*)d_in[4];
    const float* b0  = (const float*)d_in[5];
    const float* lW0 = (const float*)d_in[6];
    const float* lb0 = (const float*)d_in[7];
    const float* W1  = (const float*)d_in[8];
    const float* as1 = (const float*)d_in[9];
    const float* ad1 = (const float*)d_in[10];
    const float* b1  = (const float*)d_in[11];
    const float* lW1 = (const float*)d_in[12];
    const float* lb1 = (const float*)d_in[13];
    float* out = (float*)d_out;

    const int N = in_sizes[0] / 128;
    const int E = in_sizes[1] / 2;
    const int T = E + N;
    const int NBK = (N + 255) >> 8;      // used buckets (196)

    // workspace carve-up (256B aligned), ~38 MB
    char* w = (char*)d_ws;
    auto alloc = [&](size_t bytes) -> char* {
        char* p = w; w += (bytes + 255) / 256 * 256; return p;
    };
    int* rowstart  = (int*)alloc((size_t)(N + 1) * 4);
    int* gcur      = (int*)alloc(NBUCK * 4);
    int* bbase     = (int*)alloc(NBUCK * 4);
    unsigned int* bucketed = (unsigned int*)alloc((size_t)NBUCK * BCAP * 4);
    unsigned short* esrc = (unsigned short*)alloc((size_t)T * 2);
    float* aS      = (float*)alloc((size_t)N * 4 * 4);    // layer0 [N,4]; layer1 [N]
    float* aD      = (float*)alloc((size_t)N * 4 * 4);
    __hip_bfloat16* hbuf = (__hip_bfloat16*)alloc((size_t)N * 128 * 2); // h0 / h1
    __hip_bfloat16* h1in = (__hip_bfloat16*)alloc((size_t)N * 128 * 2); // skip0 -> ELU
    short* Wp0  = (short*)alloc(16384 * 2);
    short* lWp0 = (short*)alloc(16384 * 2);
    short* Wp1  = (short*)alloc(4096 * 2);
    short* lWp1 = (short*)alloc(4096 * 2);
    float* bc0  = (float*)alloc(128 * 4);
    float* bc1  = (float*)alloc(32 * 4);

    // init (bucket cursors + packed weights + combined biases)
    k_init<<<64, 256, 0, stream>>>(W0, lW0, W1, lW1, b0, lb0, b1, lb1,
                                   Wp0, lWp0, Wp1, lWp1, bc0, bc1, gcur);
    // CSR via bucket sort
    k_bucket<<<(T + 2047) / 2048, 256, 0, stream>>>(ei, gcur, bucketed, E, T);
    k_bscan<<<1, NBUCK, 0, stream>>>(gcur, bbase, rowstart, N);
    k_fill2<<<NBK, 256, 0, stream>>>(bucketed, gcur, bbase, rowstart, esrc, N);

    // layer 0 (att fused into gemm)
    k_gemm0<<<(N + 63) / 64, 256, 0, stream>>>(x, Wp0, lWp0, as0, ad0,
                                               hbuf, h1in, aS, aD, N);
    k_agg0<<<(N + 3) / 4, 256, 0, stream>>>(rowstart, esrc, (const unsigned int*)hbuf,
                                            aS, aD, bc0, (unsigned int*)h1in, N);
    // layer 1 (h1 reuses hbuf; skip1 lives in d_out f32; att fused)
    k_gemm1<<<(N + 63) / 64, 256, 0, stream>>>(h1in, Wp1, lWp1, as1, ad1,
                                               hbuf, out, aS, aD, N);
    k_agg1<<<(N + 3) / 4, 256, 0, stream>>>(rowstart, esrc, hbuf, aS, aD,
                                            bc1, out, N);
}